// Round 1
// 202.405 us; speedup vs baseline: 1.0137x; 1.0137x over previous
//
#include <hip/hip_runtime.h>

// Problem constants
constexpr int Bc = 256;   // batch
constexpr int Nc = 512;   // nodes
constexpr int Dc = 256;   // dim_graph == dim_desc
constexpr int Rc = 64;    // rank
constexpr int SPLIT = 4;  // N-splits per b in the hot kernel (4 -> 1024 blocks = one residency round)
constexpr int ROWS = Nc / SPLIT;    // 128 rows per k1 block
constexpr int NSTEP = ROWS / 16;    // 8 row-steps per team

typedef float f4 __attribute__((ext_vector_type(4)));

// Workspace layout (floats)
constexpr size_t WS_P = 0;                        // p[B][D]         : 65536
constexpr size_t WS_L = WS_P + (size_t)Bc * Dc;   // l_part[B][S]    : 1024
constexpr size_t WS_H = WS_L + (size_t)Bc * SPLIT;            // h_part[B][S][D] : 262144
constexpr size_t WS_FLOATS = WS_H + (size_t)Bc * SPLIT * Dc;  // total 328704

// ---------------------------------------------------------------- kernel 0
// p[b][d] = sum_r (tokns_k[b]·Wq[r]) * Wk[r][d]
__global__ __launch_bounds__(256) void k0_precompute_p(
    const float* __restrict__ tokns_k, const float* __restrict__ Wq,
    const float* __restrict__ Wk, float* __restrict__ ws)
{
    const int b = blockIdx.x;
    const int t = threadIdx.x;
    const int wave = t >> 6, lane = t & 63, g = lane >> 4, l16 = lane & 15;

    __shared__ float q_s[Rc];

    #pragma unroll
    for (int step = 0; step < 4; ++step) {
        const int r = wave * 16 + step * 4 + g;
        float acc = 0.0f;
        #pragma unroll
        for (int j = 0; j < 4; ++j) {
            const float4 tk = *(const float4*)(tokns_k + b * Dc + l16 * 4 + j * 64);
            const float4 wq = *(const float4*)(Wq + r * Dc + l16 * 4 + j * 64);
            acc += tk.x * wq.x + tk.y * wq.y + tk.z * wq.z + tk.w * wq.w;
        }
        #pragma unroll
        for (int off = 1; off < 16; off <<= 1) acc += __shfl_xor(acc, off);
        if (l16 == 0) q_s[r] = acc;
    }
    __syncthreads();

    float acc = 0.0f;
    #pragma unroll 8
    for (int r = 0; r < Rc; ++r) acc += q_s[r] * Wk[r * Dc + t];
    ws[WS_P + (size_t)b * Dc + t] = acc;
}

// ---------------------------------------------------------------- kernel 1
// Single nt-load pass over H, 16-lane teams, mask-skipped rows.
// NEW this round: explicit 2-deep double-buffered load pipeline (xa/xb) so the
// next row's 4 global loads are issued BEFORE the current row's waitcnt+shuffle
// chain; mask hoisted into a register bitmap. Bit-identical math to validated R6.
__global__ __launch_bounds__(256) void k1_stream(
    const float* __restrict__ H_pad, const int* __restrict__ mask,
    const float* __restrict__ log_scale, float* __restrict__ ws,
    float* __restrict__ out)
{
    const int s = blockIdx.x;    // split
    const int b = blockIdx.y;    // batch
    const int t = threadIdx.x;
    const int wave = t >> 6, lane = t & 63, g = lane >> 4, l16 = lane & 15;
    const int n0 = s * ROWS;
    const int team = wave * 4 + g;   // 16 teams of 16 lanes

    __shared__ __align__(16) float hm[16][Dc];   // 16 team partials, 16 KB
    __shared__ float l_s[16];
    __shared__ float scores_s[ROWS];
    __shared__ int   mask_s[ROWS];

    if (t < ROWS) mask_s[t] = mask[b * Nc + n0 + t];

    const float inv_scale = 1.0f / fmaxf(__expf(log_scale[0]), 0.1f);

    // per-lane p fragment (16 floats covering cols l16*4 + j*64)
    const float* __restrict__ pb = ws + WS_P + (size_t)b * Dc;
    float4 p4[4];
    #pragma unroll
    for (int j = 0; j < 4; ++j) p4[j] = *(const float4*)(pb + l16 * 4 + j * 64);
    __syncthreads();

    // hoist this team's 8 mask bits into a register bitmap
    int actbits = 0;
    #pragma unroll
    for (int k = 0; k < NSTEP; ++k)
        actbits |= (mask_s[k * 16 + team] != 0) ? (1 << k) : 0;

    const float* __restrict__ Hb = H_pad + ((size_t)b * Nc + n0) * Dc;
    float  l_acc = 0.0f;
    float4 h4[4];
    #pragma unroll
    for (int j = 0; j < 4; ++j) h4[j] = make_float4(0.f, 0.f, 0.f, 0.f);

    auto LOADROW = [&](f4 (&x)[4], int nr, bool act) {
        if (act) {
            const float* __restrict__ row = Hb + nr * Dc + l16 * 4;
            #pragma unroll
            for (int j = 0; j < 4; ++j)
                x[j] = __builtin_nontemporal_load((const f4*)(row + j * 64));
        }
    };
    auto PROCROW = [&](const f4 (&x)[4], int nr, bool act) {
        if (!act) {
            // masked out: alpha exactly 0, h/l contributions exactly 0 — no load done
            if (l16 == 0) scores_s[nr] = -1e30f;
            return;
        }
        float s0 = x[0][0] * p4[0].x + x[0][1] * p4[0].y + x[0][2] * p4[0].z + x[0][3] * p4[0].w;
        float s1 = x[1][0] * p4[1].x + x[1][1] * p4[1].y + x[1][2] * p4[1].z + x[1][3] * p4[1].w;
        float s2 = x[2][0] * p4[2].x + x[2][1] * p4[2].y + x[2][2] * p4[2].z + x[2][3] * p4[2].w;
        float s3 = x[3][0] * p4[3].x + x[3][1] * p4[3].y + x[3][2] * p4[3].z + x[3][3] * p4[3].w;
        float sc = (s0 + s1) + (s2 + s3);
        #pragma unroll
        for (int off = 1; off < 16; off <<= 1) sc += __shfl_xor(sc, off);
        sc *= inv_scale;
        if (l16 == 0) scores_s[nr] = sc;

        const float pn = __expf(sc);     // |scores| << 88: no overflow (validated R2-R6)
        l_acc += pn;
        #pragma unroll
        for (int j = 0; j < 4; ++j) {
            h4[j].x = fmaf(pn, x[j][0], h4[j].x);
            h4[j].y = fmaf(pn, x[j][1], h4[j].y);
            h4[j].z = fmaf(pn, x[j][2], h4[j].z);
            h4[j].w = fmaf(pn, x[j][3], h4[j].w);
        }
    };

    // 2-deep software pipeline over 8 row-steps (statically indexed buffers)
    f4 xa[4], xb[4];
    LOADROW(xa, team, (actbits >> 0) & 1);
    #pragma unroll
    for (int it = 0; it < NSTEP / 2; ++it) {
        const int nrA = it * 32 + team;
        const int nrB = nrA + 16;
        const bool actA = (actbits >> (2 * it)) & 1;
        const bool actB = (actbits >> (2 * it + 1)) & 1;
        LOADROW(xb, nrB, actB);                 // prefetch odd row before waiting on even
        PROCROW(xa, nrA, actA);
        if (it + 1 < NSTEP / 2)
            LOADROW(xa, nrA + 32, (actbits >> (2 * it + 2)) & 1);
        PROCROW(xb, nrB, actB);
    }

    // publish 16 team partials
    #pragma unroll
    for (int j = 0; j < 4; ++j) *(float4*)(&hm[team][l16 * 4 + j * 64]) = h4[j];
    if (l16 == 0) l_s[team] = l_acc;
    __syncthreads();

    // reduce and write this block's partial
    if (t < ROWS) out[b * Nc + n0 + t] = scores_s[t];   // raw scores (k2 normalizes)
    float hsum = 0.0f;
    #pragma unroll
    for (int p = 0; p < 16; ++p) hsum += hm[p][t];
    ws[WS_H + ((size_t)b * SPLIT + s) * Dc + t] = hsum;
    if (t == 0) {
        float L = 0.0f;
        #pragma unroll
        for (int p = 0; p < 16; ++p) L += l_s[p];
        ws[WS_L + (size_t)b * SPLIT + s] = L;
    }
}

// ---------------------------------------------------------------- kernel 2
// Merge partials: normalize alpha in-place, hbar, ctx = hbar @ Wv^T.
__global__ __launch_bounds__(256) void k2_merge(
    const float* __restrict__ Wv, const float* __restrict__ ws,
    float* __restrict__ out)
{
    const int b = blockIdx.x;
    const int t = threadIdx.x;
    const int wave = t >> 6, lane = t & 63, g = lane >> 4, l16 = lane & 15;

    __shared__ __align__(16) float hbar[Dc];

    float L = 0.0f;
    #pragma unroll
    for (int s = 0; s < SPLIT; ++s) L += ws[WS_L + (size_t)b * SPLIT + s];
    const float invL = 1.0f / L;

    float hacc = 0.0f;
    #pragma unroll
    for (int s = 0; s < SPLIT; ++s) hacc += ws[WS_H + ((size_t)b * SPLIT + s) * Dc + t];
    hbar[t] = hacc * invL;

    // normalize alpha in place (raw scores were written by k1)
    #pragma unroll
    for (int i = 0; i < Nc / 256; ++i) {
        const int idx = b * Nc + i * 256 + t;
        out[idx] = __expf(out[idx]) * invL;
    }
    __syncthreads();

    float4 hb4[4];
    #pragma unroll
    for (int j = 0; j < 4; ++j) hb4[j] = *(const float4*)(hbar + l16 * 4 + j * 64);
    float* __restrict__ ctx_out = out + (size_t)Bc * Nc + b * Dc;
    #pragma unroll
    for (int step = 0; step < 16; ++step) {
        const int e = step * 16 + wave * 4 + g;
        float acc = 0.0f;
        #pragma unroll
        for (int j = 0; j < 4; ++j) {
            const float4 wv = *(const float4*)(Wv + e * Dc + l16 * 4 + j * 64);
            acc += wv.x * hb4[j].x + wv.y * hb4[j].y + wv.z * hb4[j].z + wv.w * hb4[j].w;
        }
        #pragma unroll
        for (int off = 1; off < 16; off <<= 1) acc += __shfl_xor(acc, off);
        if (l16 == 0) ctx_out[e] = acc;
    }
}

// ---------------------------------------------------------------- fallback
// Round-2 single-kernel version (passed validation) for small ws_size.
constexpr int FNT = 512;
constexpr int FNW = FNT / 64;
constexpr int FNPW = Nc / FNW;

__global__ __launch_bounds__(FNT) void fba_fallback(
    const float* __restrict__ tokns_k, const float* __restrict__ H_pad,
    const int* __restrict__ mask, const float* __restrict__ Wq,
    const float* __restrict__ Wk, const float* __restrict__ Wv,
    const float* __restrict__ log_scale, float* __restrict__ out)
{
    const int b = blockIdx.x, t = threadIdx.x;
    const int wave = t >> 6, lane = t & 63;

    __shared__ __align__(16) float q_s[Rc];
    __shared__ __align__(16) float p_s[Dc];
    __shared__ __align__(16) float scores_s[Nc];
    __shared__ __align__(16) float hmerge[FNW][Dc];
    __shared__ float l_s[FNW];
    __shared__ __align__(16) float hbar[Dc];
    __shared__ int mask_s[Nc];

    const float inv_scale = 1.0f / fmaxf(__expf(log_scale[0]), 0.1f);

    const float4 tok4 = *(const float4*)(tokns_k + b * Dc + lane * 4);
    #pragma unroll
    for (int i = 0; i < Rc / FNW; ++i) {
        const int r = wave * (Rc / FNW) + i;
        const float4 w4 = *(const float4*)(Wq + r * Dc + lane * 4);
        float s = w4.x * tok4.x + w4.y * tok4.y + w4.z * tok4.z + w4.w * tok4.w;
        #pragma unroll
        for (int off = 32; off >= 1; off >>= 1) s += __shfl_xor(s, off);
        if (lane == 0) q_s[r] = s;
    }
    mask_s[t] = mask[b * Nc + t];
    mask_s[t + FNT] = mask[b * Nc + t + FNT];
    __syncthreads();

    if (t < Dc) {
        float acc = 0.0f;
        #pragma unroll 8
        for (int r = 0; r < Rc; ++r) acc += q_s[r] * Wk[r * Dc + t];
        p_s[t] = acc;
    }
    __syncthreads();

    const float4 p4 = *(const float4*)(p_s + lane * 4);
    const float* Hb = H_pad + (size_t)b * Nc * Dc;
    float l_acc = 0.0f;
    float4 h4 = make_float4(0.f, 0.f, 0.f, 0.f);

    for (int i = 0; i < FNPW; ++i) {
        const int n = wave * FNPW + i;
        const float4 x4 = *(const float4*)(Hb + n * Dc + lane * 4);
        float s = x4.x * p4.x + x4.y * p4.y + x4.z * p4.z + x4.w * p4.w;
        #pragma unroll
        for (int off = 32; off >= 1; off >>= 1) s += __shfl_xor(s, off);
        s *= inv_scale;
        if (mask_s[n] == 0) s = -1e30f;
        if (lane == 0) scores_s[n] = s;
        const float pn = __expf(s);
        l_acc += pn;
        h4.x = fmaf(pn, x4.x, h4.x); h4.y = fmaf(pn, x4.y, h4.y);
        h4.z = fmaf(pn, x4.z, h4.z); h4.w = fmaf(pn, x4.w, h4.w);
    }

    if (lane == 0) l_s[wave] = l_acc;
    *(float4*)(&hmerge[wave][lane * 4]) = h4;
    __syncthreads();

    float L = 0.0f;
    #pragma unroll
    for (int w = 0; w < FNW; ++w) L += l_s[w];
    const float invL = 1.0f / L;

    if (t < Dc) {
        float acc = 0.0f;
        #pragma unroll
        for (int w = 0; w < FNW; ++w) acc += hmerge[w][t];
        hbar[t] = acc * invL;
    }
    out[b * Nc + t] = __expf(scores_s[t]) * invL;
    out[b * Nc + t + FNT] = __expf(scores_s[t + FNT]) * invL;
    __syncthreads();

    const float4 hb4 = *(const float4*)(hbar + lane * 4);
    float* ctx_out = out + (size_t)Bc * Nc + b * Dc;
    #pragma unroll
    for (int i = 0; i < Dc / FNW; ++i) {
        const int e = wave * (Dc / FNW) + i;
        const float4 w4 = *(const float4*)(Wv + e * Dc + lane * 4);
        float s = w4.x * hb4.x + w4.y * hb4.y + w4.z * hb4.z + w4.w * hb4.w;
        #pragma unroll
        for (int off = 32; off >= 1; off >>= 1) s += __shfl_xor(s, off);
        if (lane == 0) ctx_out[e] = s;
    }
}

extern "C" void kernel_launch(void* const* d_in, const int* in_sizes, int n_in,
                              void* d_out, int out_size, void* d_ws, size_t ws_size,
                              hipStream_t stream) {
    const float* tokns_k   = (const float*)d_in[0];
    const float* H_pad     = (const float*)d_in[1];
    const int*   mask      = (const int*)d_in[2];
    const float* Wq        = (const float*)d_in[3];
    const float* Wk        = (const float*)d_in[4];
    const float* Wv        = (const float*)d_in[5];
    const float* log_scale = (const float*)d_in[6];
    float* out = (float*)d_out;

    if (ws_size >= WS_FLOATS * sizeof(float)) {
        float* ws = (float*)d_ws;
        k0_precompute_p<<<Bc, 256, 0, stream>>>(tokns_k, Wq, Wk, ws);
        dim3 grid1(SPLIT, Bc);
        k1_stream<<<grid1, 256, 0, stream>>>(H_pad, mask, log_scale, ws, out);
        k2_merge<<<Bc, 256, 0, stream>>>(Wv, ws, out);
    } else {
        fba_fallback<<<Bc, FNT, 0, stream>>>(tokns_k, H_pad, mask, Wq, Wk, Wv,
                                             log_scale, out);
    }
}

// Round 2
// 192.157 us; speedup vs baseline: 1.0678x; 1.0533x over previous
//
#include <hip/hip_runtime.h>

// Problem constants
constexpr int Bc = 256;   // batch
constexpr int Nc = 512;   // nodes
constexpr int Dc = 256;   // dim_graph == dim_desc
constexpr int Rc = 64;    // rank

constexpr int NT    = 512;          // threads per block (8 waves)
constexpr int NTEAM = 32;           // 16-lane teams per block
constexpr int NSTEP = Nc / NTEAM;   // 16 rows per team

typedef float f4 __attribute__((ext_vector_type(4)));

// ---------------------------------------------------------------- fused kernel
// One block per batch element b. Phases:
//   1. q = tokns_k[b] @ Wq^T            (32 teams, 2 rows each)
//   2. p = q @ Wk                       (t<256, L2-resident Wk)
//   3. stream H rows: score, exp, h/l accumulate
//      - 16-lane teams, mask bitmap, 2-deep statically-indexed load pipeline
//      - masked rows: NO load, alpha exactly 0 (validated R6/R1 semantics)
//   4. reduce 32 team partials, write alpha = exp(score)*invL, hbar
//   5. ctx = hbar @ Wv^T
// Workspace is NOT used anywhere.
__global__ __launch_bounds__(NT) void fba_fused(
    const float* __restrict__ tokns_k, const float* __restrict__ H_pad,
    const int* __restrict__ mask, const float* __restrict__ Wq,
    const float* __restrict__ Wk, const float* __restrict__ Wv,
    const float* __restrict__ log_scale, float* __restrict__ out)
{
    const int b = blockIdx.x;
    const int t = threadIdx.x;
    const int wave = t >> 6, lane = t & 63, g = lane >> 4, l16 = lane & 15;
    const int team = wave * 4 + g;     // 0..31

    __shared__ float q_s[Rc];
    __shared__ __align__(16) float p_s[Dc];
    __shared__ __align__(16) float hm[NTEAM][Dc];   // 32 KB team partials
    __shared__ float l_s[NTEAM];
    __shared__ float scores_s[Nc];                  // raw scores (LDS only!)
    __shared__ __align__(16) float hbar[Dc];
    __shared__ int   mask_s[Nc];

    mask_s[t] = mask[b * Nc + t];

    const float inv_scale = 1.0f / fmaxf(__expf(log_scale[0]), 0.1f);

    // -------- phase 1: q[r] = tokns_k[b] . Wq[r]
    #pragma unroll
    for (int step = 0; step < 2; ++step) {
        const int r = step * NTEAM + team;
        float acc = 0.0f;
        #pragma unroll
        for (int j = 0; j < 4; ++j) {
            const float4 tk = *(const float4*)(tokns_k + b * Dc + l16 * 4 + j * 64);
            const float4 wq = *(const float4*)(Wq + r * Dc + l16 * 4 + j * 64);
            acc += tk.x * wq.x + tk.y * wq.y + tk.z * wq.z + tk.w * wq.w;
        }
        #pragma unroll
        for (int off = 1; off < 16; off <<= 1) acc += __shfl_xor(acc, off);
        if (l16 == 0) q_s[r] = acc;
    }
    __syncthreads();

    // -------- phase 2: p[d] = sum_r q[r] * Wk[r][d]   (Wk is L2-resident)
    if (t < Dc) {
        float acc = 0.0f;
        #pragma unroll 16
        for (int r = 0; r < Rc; ++r) acc += q_s[r] * Wk[r * Dc + t];
        p_s[t] = acc;
    }
    __syncthreads();

    // per-lane p fragment (16 floats covering cols l16*4 + j*64)
    float4 p4[4];
    #pragma unroll
    for (int j = 0; j < 4; ++j) p4[j] = *(const float4*)(p_s + l16 * 4 + j * 64);

    // hoist this team's 16 mask bits into a register bitmap
    int actbits = 0;
    #pragma unroll
    for (int k = 0; k < NSTEP; ++k)
        actbits |= (mask_s[k * NTEAM + team] != 0) ? (1 << k) : 0;

    // -------- phase 3: stream H rows
    const float* __restrict__ Hb = H_pad + (size_t)b * Nc * Dc;
    float  l_acc = 0.0f;
    float4 h4[4];
    #pragma unroll
    for (int j = 0; j < 4; ++j) h4[j] = make_float4(0.f, 0.f, 0.f, 0.f);

    auto LOADROW = [&](f4 (&x)[4], int nr, bool act) {
        if (act) {
            const float* __restrict__ row = Hb + nr * Dc + l16 * 4;
            #pragma unroll
            for (int j = 0; j < 4; ++j)
                x[j] = __builtin_nontemporal_load((const f4*)(row + j * 64));
        }
    };
    auto PROCROW = [&](const f4 (&x)[4], int nr, bool act) {
        if (!act) {
            // masked out: alpha exactly 0, h/l contributions exactly 0 — no load done
            if (l16 == 0) scores_s[nr] = -1e30f;
            return;
        }
        float s0 = x[0][0] * p4[0].x + x[0][1] * p4[0].y + x[0][2] * p4[0].z + x[0][3] * p4[0].w;
        float s1 = x[1][0] * p4[1].x + x[1][1] * p4[1].y + x[1][2] * p4[1].z + x[1][3] * p4[1].w;
        float s2 = x[2][0] * p4[2].x + x[2][1] * p4[2].y + x[2][2] * p4[2].z + x[2][3] * p4[2].w;
        float s3 = x[3][0] * p4[3].x + x[3][1] * p4[3].y + x[3][2] * p4[3].z + x[3][3] * p4[3].w;
        float sc = (s0 + s1) + (s2 + s3);
        #pragma unroll
        for (int off = 1; off < 16; off <<= 1) sc += __shfl_xor(sc, off);
        sc *= inv_scale;
        if (l16 == 0) scores_s[nr] = sc;

        const float pn = __expf(sc);     // |scores| << 88: no overflow (validated R2-R6)
        l_acc += pn;
        #pragma unroll
        for (int j = 0; j < 4; ++j) {
            h4[j].x = fmaf(pn, x[j][0], h4[j].x);
            h4[j].y = fmaf(pn, x[j][1], h4[j].y);
            h4[j].z = fmaf(pn, x[j][2], h4[j].z);
            h4[j].w = fmaf(pn, x[j][3], h4[j].w);
        }
    };

    // 2-deep software pipeline over 16 row-steps (statically indexed buffers)
    f4 xa[4], xb[4];
    LOADROW(xa, team, (actbits >> 0) & 1);
    #pragma unroll
    for (int it = 0; it < NSTEP / 2; ++it) {
        const int nrA = it * (2 * NTEAM) + team;
        const int nrB = nrA + NTEAM;
        const bool actA = (actbits >> (2 * it)) & 1;
        const bool actB = (actbits >> (2 * it + 1)) & 1;
        LOADROW(xb, nrB, actB);                 // prefetch odd row before waiting on even
        PROCROW(xa, nrA, actA);
        if (it + 1 < NSTEP / 2)
            LOADROW(xa, nrA + 2 * NTEAM, (actbits >> (2 * it + 2)) & 1);
        PROCROW(xb, nrB, actB);
    }

    // publish 32 team partials
    #pragma unroll
    for (int j = 0; j < 4; ++j) *(float4*)(&hm[team][l16 * 4 + j * 64]) = h4[j];
    if (l16 == 0) l_s[team] = l_acc;
    __syncthreads();

    // -------- phase 4: merge partials, alpha, hbar
    float L = 0.0f;
    #pragma unroll
    for (int p = 0; p < NTEAM; ++p) L += l_s[p];   // broadcast reads, conflict-free
    const float invL = 1.0f / L;

    if (t < Dc) {
        float hsum = 0.0f;
        #pragma unroll
        for (int p = 0; p < NTEAM; ++p) hsum += hm[p][t];
        hbar[t] = hsum * invL;
    }
    out[b * Nc + t] = __expf(scores_s[t]) * invL;   // alpha, one store/thread
    __syncthreads();

    // -------- phase 5: ctx = hbar @ Wv^T
    float4 hb4[4];
    #pragma unroll
    for (int j = 0; j < 4; ++j) hb4[j] = *(const float4*)(hbar + l16 * 4 + j * 64);
    float* __restrict__ ctx_out = out + (size_t)Bc * Nc + b * Dc;
    #pragma unroll
    for (int step = 0; step < Dc / NTEAM; ++step) {
        const int e = step * NTEAM + team;
        float acc = 0.0f;
        #pragma unroll
        for (int j = 0; j < 4; ++j) {
            const float4 wv = *(const float4*)(Wv + e * Dc + l16 * 4 + j * 64);
            acc += wv.x * hb4[j].x + wv.y * hb4[j].y + wv.z * hb4[j].z + wv.w * hb4[j].w;
        }
        #pragma unroll
        for (int off = 1; off < 16; off <<= 1) acc += __shfl_xor(acc, off);
        if (l16 == 0) ctx_out[e] = acc;
    }
}

extern "C" void kernel_launch(void* const* d_in, const int* in_sizes, int n_in,
                              void* d_out, int out_size, void* d_ws, size_t ws_size,
                              hipStream_t stream) {
    const float* tokns_k   = (const float*)d_in[0];
    const float* H_pad     = (const float*)d_in[1];
    const int*   mask      = (const int*)d_in[2];
    const float* Wq        = (const float*)d_in[3];
    const float* Wk        = (const float*)d_in[4];
    const float* Wv        = (const float*)d_in[5];
    const float* log_scale = (const float*)d_in[6];
    float* out = (float*)d_out;
    (void)d_ws; (void)ws_size;   // workspace intentionally untouched

    fba_fused<<<Bc, NT, 0, stream>>>(tokns_k, H_pad, mask, Wq, Wk, Wv,
                                     log_scale, out);
}

// Round 3
// 187.392 us; speedup vs baseline: 1.0950x; 1.0254x over previous
//
#include <hip/hip_runtime.h>

// Problem constants
constexpr int Bc = 256;   // batch
constexpr int Nc = 512;   // nodes
constexpr int Dc = 256;   // dim_graph == dim_desc
constexpr int Rc = 64;    // rank

constexpr int NT    = 1024;         // threads per block (16 waves -> 4 waves/SIMD)
constexpr int NTEAM = 64;           // 16-lane teams per block
constexpr int NSTEP = Nc / NTEAM;   // 8 rows per team

typedef float f4 __attribute__((ext_vector_type(4)));

// ---------------------------------------------------------------- fused kernel
// One block per batch element b, 1024 threads (16 waves/CU vs 8 in R2).
//   1. q = tokns_k[b] @ Wq^T            (64 teams, 1 row each)
//   2. p = q @ Wk                       (ALL 16 waves via LDS partials)
//   3. stream H rows: score, exp, h/l accumulate
//      - 16-lane teams, mask bitmap, 2-deep statically-indexed load pipeline
//      - masked rows: NO load, alpha exactly 0 (validated R6/R1/R2 semantics)
//      - stores pn = exp(sc) to LDS (masked: exact 0.0f) — no epilogue exp
//   4. reduce 64 team partials, write alpha = pn*invL, hbar
//   5. ctx = hbar @ Wv^T
// Workspace is NOT used anywhere.
__global__ __launch_bounds__(NT) void fba_fused(
    const float* __restrict__ tokns_k, const float* __restrict__ H_pad,
    const int* __restrict__ mask, const float* __restrict__ Wq,
    const float* __restrict__ Wk, const float* __restrict__ Wv,
    const float* __restrict__ log_scale, float* __restrict__ out)
{
    const int b = blockIdx.x;
    const int t = threadIdx.x;
    const int wave = t >> 6, lane = t & 63, g = lane >> 4, l16 = lane & 15;
    const int team = wave * 4 + g;     // 0..63

    __shared__ float q_s[Rc];
    __shared__ __align__(16) float p_s[Dc];
    __shared__ __align__(16) float hm[NTEAM][Dc];   // 64 KB team partials
    __shared__ float l_s[NTEAM];
    __shared__ float pn_s[Nc];                      // exp(score) (LDS only!)
    __shared__ __align__(16) float hbar[Dc];
    __shared__ int   mask_s[Nc];

    if (t < Nc) mask_s[t] = mask[b * Nc + t];

    const float inv_scale = 1.0f / fmaxf(__expf(log_scale[0]), 0.1f);

    // -------- phase 1: q[r] = tokns_k[b] . Wq[r]   (team r handles row r)
    {
        const int r = team;
        float acc = 0.0f;
        #pragma unroll
        for (int j = 0; j < 4; ++j) {
            const float4 tk = *(const float4*)(tokns_k + b * Dc + l16 * 4 + j * 64);
            const float4 wq = *(const float4*)(Wq + r * Dc + l16 * 4 + j * 64);
            acc += tk.x * wq.x + tk.y * wq.y + tk.z * wq.z + tk.w * wq.w;
        }
        #pragma unroll
        for (int off = 1; off < 16; off <<= 1) acc += __shfl_xor(acc, off);
        if (l16 == 0) q_s[r] = acc;
    }
    __syncthreads();

    // -------- phase 2: p[d] = sum_r q[r] * Wk[r][d]  (4 r-chunks across waves)
    {
        const int rg = t >> 8;        // 0..3  (chunk of 16 r's)
        const int d  = t & 255;
        float acc = 0.0f;
        #pragma unroll
        for (int rr = 0; rr < 16; ++rr) {
            const int r = rg * 16 + rr;
            acc += q_s[r] * Wk[r * Dc + d];
        }
        hm[rg][d] = acc;              // reuse hm before phase-3 publish
    }
    __syncthreads();
    if (t < Dc) p_s[t] = (hm[0][t] + hm[1][t]) + (hm[2][t] + hm[3][t]);
    __syncthreads();

    // per-lane p fragment (16 floats covering cols l16*4 + j*64)
    float4 p4[4];
    #pragma unroll
    for (int j = 0; j < 4; ++j) p4[j] = *(const float4*)(p_s + l16 * 4 + j * 64);

    // hoist this team's 8 mask bits into a register bitmap
    int actbits = 0;
    #pragma unroll
    for (int k = 0; k < NSTEP; ++k)
        actbits |= (mask_s[k * NTEAM + team] != 0) ? (1 << k) : 0;

    // -------- phase 3: stream H rows
    const float* __restrict__ Hb = H_pad + (size_t)b * Nc * Dc;
    float  l_acc = 0.0f;
    float4 h4[4];
    #pragma unroll
    for (int j = 0; j < 4; ++j) h4[j] = make_float4(0.f, 0.f, 0.f, 0.f);

    auto LOADROW = [&](f4 (&x)[4], int nr, bool act) {
        if (act) {
            const float* __restrict__ row = Hb + nr * Dc + l16 * 4;
            #pragma unroll
            for (int j = 0; j < 4; ++j)
                x[j] = __builtin_nontemporal_load((const f4*)(row + j * 64));
        }
    };
    auto PROCROW = [&](const f4 (&x)[4], int nr, bool act) {
        if (!act) {
            // masked out: alpha exactly 0 (== exp(-1e30)*invL), no load done
            if (l16 == 0) pn_s[nr] = 0.0f;
            return;
        }
        float s0 = x[0][0] * p4[0].x + x[0][1] * p4[0].y + x[0][2] * p4[0].z + x[0][3] * p4[0].w;
        float s1 = x[1][0] * p4[1].x + x[1][1] * p4[1].y + x[1][2] * p4[1].z + x[1][3] * p4[1].w;
        float s2 = x[2][0] * p4[2].x + x[2][1] * p4[2].y + x[2][2] * p4[2].z + x[2][3] * p4[2].w;
        float s3 = x[3][0] * p4[3].x + x[3][1] * p4[3].y + x[3][2] * p4[3].z + x[3][3] * p4[3].w;
        float sc = (s0 + s1) + (s2 + s3);
        #pragma unroll
        for (int off = 1; off < 16; off <<= 1) sc += __shfl_xor(sc, off);
        sc *= inv_scale;

        const float pn = __expf(sc);     // |scores| << 88: no overflow (validated R2-R6)
        if (l16 == 0) pn_s[nr] = pn;
        l_acc += pn;
        #pragma unroll
        for (int j = 0; j < 4; ++j) {
            h4[j].x = fmaf(pn, x[j][0], h4[j].x);
            h4[j].y = fmaf(pn, x[j][1], h4[j].y);
            h4[j].z = fmaf(pn, x[j][2], h4[j].z);
            h4[j].w = fmaf(pn, x[j][3], h4[j].w);
        }
    };

    // 2-deep software pipeline over 8 row-steps (statically indexed buffers)
    f4 xa[4], xb[4];
    LOADROW(xa, team, (actbits >> 0) & 1);
    #pragma unroll
    for (int it = 0; it < NSTEP / 2; ++it) {
        const int nrA = it * (2 * NTEAM) + team;
        const int nrB = nrA + NTEAM;
        const bool actA = (actbits >> (2 * it)) & 1;
        const bool actB = (actbits >> (2 * it + 1)) & 1;
        LOADROW(xb, nrB, actB);                 // prefetch odd row before waiting on even
        PROCROW(xa, nrA, actA);
        if (it + 1 < NSTEP / 2)
            LOADROW(xa, nrA + 2 * NTEAM, (actbits >> (2 * it + 2)) & 1);
        PROCROW(xb, nrB, actB);
    }

    // publish 64 team partials
    #pragma unroll
    for (int j = 0; j < 4; ++j) *(float4*)(&hm[team][l16 * 4 + j * 64]) = h4[j];
    if (l16 == 0) l_s[team] = l_acc;
    __syncthreads();

    // -------- phase 4: merge partials, alpha, hbar
    float L = 0.0f;
    #pragma unroll
    for (int p = 0; p < NTEAM; ++p) L += l_s[p];   // broadcast reads, conflict-free
    const float invL = 1.0f / L;

    if (t < Dc) {
        float hsum = 0.0f;
        #pragma unroll
        for (int p = 0; p < NTEAM; ++p) hsum += hm[p][t];
        hbar[t] = hsum * invL;
    }
    if (t < Nc) out[b * Nc + t] = pn_s[t] * invL;   // alpha
    __syncthreads();

    // -------- phase 5: ctx = hbar @ Wv^T
    float4 hb4[4];
    #pragma unroll
    for (int j = 0; j < 4; ++j) hb4[j] = *(const float4*)(hbar + l16 * 4 + j * 64);
    float* __restrict__ ctx_out = out + (size_t)Bc * Nc + b * Dc;
    #pragma unroll
    for (int step = 0; step < Dc / NTEAM; ++step) {
        const int e = step * NTEAM + team;
        float acc = 0.0f;
        #pragma unroll
        for (int j = 0; j < 4; ++j) {
            const float4 wv = *(const float4*)(Wv + e * Dc + l16 * 4 + j * 64);
            acc += wv.x * hb4[j].x + wv.y * hb4[j].y + wv.z * hb4[j].z + wv.w * hb4[j].w;
        }
        #pragma unroll
        for (int off = 1; off < 16; off <<= 1) acc += __shfl_xor(acc, off);
        if (l16 == 0) ctx_out[e] = acc;
    }
}

extern "C" void kernel_launch(void* const* d_in, const int* in_sizes, int n_in,
                              void* d_out, int out_size, void* d_ws, size_t ws_size,
                              hipStream_t stream) {
    const float* tokns_k   = (const float*)d_in[0];
    const float* H_pad     = (const float*)d_in[1];
    const int*   mask      = (const int*)d_in[2];
    const float* Wq        = (const float*)d_in[3];
    const float* Wk        = (const float*)d_in[4];
    const float* Wv        = (const float*)d_in[5];
    const float* log_scale = (const float*)d_in[6];
    float* out = (float*)d_out;
    (void)d_ws; (void)ws_size;   // workspace intentionally untouched

    fba_fused<<<Bc, NT, 0, stream>>>(tokns_k, H_pad, mask, Wq, Wk, Wv,
                                     log_scale, out);
}